// Round 8
// baseline (58.466 us; speedup 1.0000x reference)
//
#include <hip/hip_runtime.h>
#include <hip/hip_bf16.h>

#define S_LEN 2048
#define IN_D  256
#define NHEAD 16
#define HDIM  16

typedef short s8v __attribute__((ext_vector_type(8)));
typedef float f4v __attribute__((ext_vector_type(4)));
typedef float f16v __attribute__((ext_vector_type(16)));

__device__ __forceinline__ ushort f2b(float f) {
    union { float f; unsigned u; } x; x.f = f;
    unsigned r = x.u + 0x7fffu + ((x.u >> 16) & 1u);   // RNE, inputs finite
    return (ushort)(r >> 16);
}

// -------- one-shot: wt[which][n][k] = bf16(W[k][n]), vectorized stores --------
__global__ __launch_bounds__(256) void wtrans_kernel(
    const float* __restrict__ WQ, const float* __restrict__ WK,
    const float* __restrict__ WV, ushort* __restrict__ wt)
{
    const int which = blockIdx.y;
    const float* W = (which == 0) ? WQ : (which == 1) ? WK : WV;
    ushort* o = wt + which * (IN_D * NHEAD * HDIM);
    const int tid = threadIdx.x;
    const int n  = blockIdx.x * 16 + (tid & 15);
    const int kb = (tid >> 4) * 16;
    ushort tmp[16];
#pragma unroll
    for (int j = 0; j < 16; ++j)
        tmp[j] = f2b(W[(kb + j) * (NHEAD * HDIM) + n]);   // coalesced reads per j
    *(s8v*)(o + n * IN_D + kb)     = *(const s8v*)&tmp[0];
    *(s8v*)(o + n * IN_D + kb + 8) = *(const s8v*)&tmp[8];
}

// -------- projection: 1 wave = 32 rows x 32 cols x full K via 32x32x16 MFMA --------
// No LDS, no barriers, no combine. 3072 waves (3/SIMD).
// which=0: qh[B,H,S,D]*(0.25*log2e)  which=1: kh[B,H,S,D]  which=2: vt[B,H,D,S]
__global__ __launch_bounds__(256, 4) void proj_kernel(
    const float* __restrict__ Q, const float* __restrict__ K, const float* __restrict__ V,
    const ushort* __restrict__ wt,
    ushort* __restrict__ qh, ushort* __restrict__ kh, ushort* __restrict__ vt)
{
    const int which = blockIdx.y;
    const float* X = (which == 0) ? Q : (which == 1) ? K : V;
    const ushort* wb = wt + which * (IN_D * NHEAD * HDIM);

    const int tid = threadIdx.x;
    const int wv = tid >> 6, lane = tid & 63;
    const int l31 = lane & 31, hi = lane >> 5;
    const int rt = blockIdx.x >> 1;               // 128 row-tiles of 32
    const int ct = (blockIdx.x & 1) * 4 + wv;     // 8 col-tiles of 32
    const int rowA = rt * 32 + l31;
    const int col  = ct * 32 + l31;

    f16v acc = {};
#pragma unroll 4
    for (int ks = 0; ks < 16; ++ks) {
        const int k0 = ks * 16 + 8 * hi;
        const float* xp = X + (size_t)rowA * IN_D + k0;
        const f4v x0 = *(const f4v*)xp;
        const f4v x1 = *(const f4v*)(xp + 4);
        union { unsigned u[4]; s8v v; } au;
        asm("v_cvt_pk_bf16_f32 %0, %1, %2" : "=v"(au.u[0]) : "v"(x0[0]), "v"(x0[1]));
        asm("v_cvt_pk_bf16_f32 %0, %1, %2" : "=v"(au.u[1]) : "v"(x0[2]), "v"(x0[3]));
        asm("v_cvt_pk_bf16_f32 %0, %1, %2" : "=v"(au.u[2]) : "v"(x1[0]), "v"(x1[1]));
        asm("v_cvt_pk_bf16_f32 %0, %1, %2" : "=v"(au.u[3]) : "v"(x1[2]), "v"(x1[3]));
        const s8v b = *(const s8v*)(wb + (size_t)col * IN_D + k0);
        acc = __builtin_amdgcn_mfma_f32_32x32x16_bf16(au.v, b, acc, 0, 0, 0);
    }

    // C layout: col = lane&31 (= n), row = (r&3) + 8*(r>>2) + 4*hi (= s-offset)
    const int h = col >> 4, d = col & 15;
    const int bI = (rt * 32) >> 11;
    const int sbase = (rt * 32) & 2047;
    if (which == 2) {
#pragma unroll
        for (int grp = 0; grp < 4; ++grp) {       // regs 4grp..4grp+3 -> s consecutive
            unsigned long long pk = 0;
#pragma unroll
            for (int j = 0; j < 4; ++j)
                pk |= (unsigned long long)f2b(acc[grp * 4 + j]) << (16 * j);
            const int s = sbase + 8 * grp + 4 * hi;
            *(unsigned long long*)(vt + ((size_t)(bI * NHEAD + h) * HDIM + d) * S_LEN + s) = pk;
        }
    } else {
        ushort* dst = (which == 0) ? qh : kh;
        const float scale = (which == 0) ? 0.25f * 1.44269504f : 1.0f;  // 1/sqrt(D)*log2e
#pragma unroll
        for (int r = 0; r < 16; ++r) {
            const int s = sbase + (r & 3) + 8 * (r >> 2) + 4 * hi;
            dst[((size_t)(bI * NHEAD + h) * S_LEN + s) * HDIM + d] = f2b(acc[r] * scale);
        }
    }
}

// ---- causal attention (ROUND-8 PROBE: work list processed TWICE) ----
// Both numerator (acc) and denominator (acc[8] via V-rows-16/20=1.0) double, so the
// normalized output is identical. #pragma unroll 1 + MFMA dataflow force real
// re-execution. Purpose: if attn is the true bottleneck its doubled duration enters
// the rocprof top-5 (with counters) and dur_us ~doubles; if dur_us stays ~45 the
// measured time is pinned by the harness's 268MB concurrent ws-fill, not our kernels.
__global__ __launch_bounds__(256, 4) void attn_kernel(
    const ushort* __restrict__ qh, const ushort* __restrict__ kh,
    const ushort* __restrict__ vt, float* __restrict__ out)
{
    __shared__ float ol[2][4][8][64];
    __shared__ float ll[2][4][32];
    const int tid = threadIdx.x;
    const int wv = tid >> 6, lane = tid & 63;
    const int l31 = lane & 31, hi = lane >> 5;
    const int bh = blockIdx.y;
    const int qbA = blockIdx.x;                 // light stream
    const int qbB = 63 - qbA;                   // heavy stream
    const int ntA = qbA + 1, ntB = qbB + 1;     // ntA + ntB == 65

    const ushort* qp = qh + (size_t)bh * S_LEN * HDIM;
    const ushort* kp = kh + (size_t)bh * S_LEN * HDIM;
    const ushort* vp = vt + (size_t)bh * HDIM * S_LEN;

    const s8v qfA = *(const s8v*)(qp + (size_t)(qbA * 32 + l31) * HDIM + 8 * hi);
    const s8v qfB = *(const s8v*)(qp + (size_t)(qbB * 32 + l31) * HDIM + 8 * hi);
    const f16v z16 = {};
    f16v aA0 = {}, aA1 = {}, aB0 = {}, aB1 = {};

    // V rows 16,20 = 1.0 (bf16) -> acc[8] accumulates the softmax denominator
    s8v vinit = {};
    if (l31 == 16 || l31 == 20) {
#pragma unroll
        for (int j = 0; j < 8; ++j) vinit[j] = (short)0x3F80;
    }

    auto process = [&](int it) {
        const bool isB = (it < ntB);            // block/wave-uniform
        const int t  = isB ? it : it - ntB;
        const int k0 = t * 32;
        const s8v kf = *(const s8v*)(kp + (size_t)(k0 + l31) * HDIM + 8 * hi);
        s8v vf0 = vinit, vf1 = vinit;
        if (l31 < 16) {
            vf0 = *(const s8v*)(vp + (size_t)l31 * S_LEN + k0 + 8 * hi);
            vf1 = *(const s8v*)(vp + (size_t)l31 * S_LEN + k0 + 16 + 8 * hi);
        }
        const s8v qf = isB ? qfB : qfA;
        const int nt = isB ? ntB : ntA;
        const f16v st = __builtin_amdgcn_mfma_f32_32x32x16_bf16(kf, qf, z16, 0, 0, 0);
        float p[16];
#pragma unroll
        for (int r = 0; r < 16; ++r) p[r] = __builtin_amdgcn_exp2f(st[r]);
        if (t == nt - 1) {                      // diagonal tile: zero k > q
#pragma unroll
            for (int r = 0; r < 16; ++r) {
                const int kr = (r & 3) + 8 * (r >> 2) + 4 * hi;
                if (kr > l31) p[r] = 0.f;
            }
        }
        s8v pb[2];
#pragma unroll
        for (int half = 0; half < 2; ++half) {
            unsigned x0, x1, y0, y1;
            asm("v_cvt_pk_bf16_f32 %0, %1, %2" : "=v"(x0) : "v"(p[8*half+0]), "v"(p[8*half+1]));
            asm("v_cvt_pk_bf16_f32 %0, %1, %2" : "=v"(x1) : "v"(p[8*half+2]), "v"(p[8*half+3]));
            asm("v_cvt_pk_bf16_f32 %0, %1, %2" : "=v"(y0) : "v"(p[8*half+4]), "v"(p[8*half+5]));
            asm("v_cvt_pk_bf16_f32 %0, %1, %2" : "=v"(y1) : "v"(p[8*half+6]), "v"(p[8*half+7]));
            auto r0 = __builtin_amdgcn_permlane32_swap(x0, y0, false, false);
            auto r1 = __builtin_amdgcn_permlane32_swap(x1, y1, false, false);
            union { unsigned u[4]; s8v v; } bu;
            bu.u[0] = r0[0]; bu.u[1] = r1[0]; bu.u[2] = r0[1]; bu.u[3] = r1[1];
            pb[half] = bu.v;
        }
        __builtin_amdgcn_s_setprio(1);
        if (isB) {
            aB0 = __builtin_amdgcn_mfma_f32_32x32x16_bf16(vf0, pb[0], aB0, 0, 0, 0);
            aB1 = __builtin_amdgcn_mfma_f32_32x32x16_bf16(vf1, pb[1], aB1, 0, 0, 0);
        } else {
            aA0 = __builtin_amdgcn_mfma_f32_32x32x16_bf16(vf0, pb[0], aA0, 0, 0, 0);
            aA1 = __builtin_amdgcn_mfma_f32_32x32x16_bf16(vf1, pb[1], aA1, 0, 0, 0);
        }
        __builtin_amdgcn_s_setprio(0);
    };

#pragma unroll 1
    for (int rep = 0; rep < 2; ++rep) {            // PROBE: 2 identical passes
        for (int it0 = 2 * wv; it0 < 65; it0 += 8) {
            process(it0);
            if (it0 + 1 < 65) process(it0 + 1);
        }
    }

    // per-wave raw partials -> LDS (conflict-free: lane is fastest index)
#pragma unroll
    for (int j = 0; j < 8; ++j) {
        ol[0][wv][j][lane] = aB0[j] + aB1[j];
        ol[1][wv][j][lane] = aA0[j] + aA1[j];
    }
    if (hi == 0) {                               // acc[8] = denominator (rows 16/20 of V=1)
        ll[0][wv][l31] = aB0[8] + aB1[8];
        ll[1][wv][l31] = aA0[8] + aA1[8];
    }
    __syncthreads();

    if (wv < 2) {                               // wave 0 -> stream B, wave 1 -> stream A
        const int ss = wv;
        const int qw = (ss ? qbA : qbB) * 32;
        float l = (ll[ss][0][l31] + ll[ss][1][l31]) + (ll[ss][2][l31] + ll[ss][3][l31]);
        const float inv = __builtin_amdgcn_rcpf(l);
        float o[8];
#pragma unroll
        for (int j = 0; j < 8; ++j)
            o[j] = ((ol[ss][0][j][lane] + ol[ss][1][j][lane]) +
                    (ol[ss][2][j][lane] + ol[ss][3][j][lane])) * inv;
        const int b = bh >> 4, h = bh & 15;
        f4v o0, o1;
#pragma unroll
        for (int j = 0; j < 4; ++j) { o0[j] = o[j]; o1[j] = o[4 + j]; }
        float* op = out + ((size_t)b * S_LEN + qw + l31) * (NHEAD * HDIM) + h * HDIM;
        *(f4v*)(op + 4 * hi) = o0;        // d = 4*hi + 0..3
        *(f4v*)(op + 8 + 4 * hi) = o1;    // d = 8 + 4*hi + 0..3
    }
}

extern "C" void kernel_launch(void* const* d_in, const int* in_sizes, int n_in,
                              void* d_out, int out_size, void* d_ws, size_t ws_size,
                              hipStream_t stream)
{
    const float* Q  = (const float*)d_in[0];
    const float* K  = (const float*)d_in[1];
    const float* V  = (const float*)d_in[2];
    const float* WQ = (const float*)d_in[3];
    const float* WK = (const float*)d_in[4];
    const float* WV = (const float*)d_in[5];
    float* out = (float*)d_out;

    const size_t mat = (size_t)2 * NHEAD * S_LEN * HDIM;   // 2 MB bf16 each
    ushort* qh = (ushort*)d_ws;
    ushort* kh = qh + mat;
    ushort* vt = kh + mat;
    ushort* wt = vt + mat;                                  // 3 x 128 KB

    wtrans_kernel<<<dim3(16, 3), 256, 0, stream>>>(WQ, WK, WV, wt);
    proj_kernel<<<dim3(256, 3), 256, 0, stream>>>(Q, K, V, wt, qh, kh, vt);
    attn_kernel<<<dim3(S_LEN / 64, 2 * NHEAD), 256, 0, stream>>>(qh, kh, vt, out);
}

// Round 9
// 40.946 us; speedup vs baseline: 1.4279x; 1.4279x over previous
//
#include <hip/hip_runtime.h>
#include <hip/hip_bf16.h>

#define S_LEN 2048
#define IN_D  256
#define NHEAD 16
#define HDIM  16

typedef short s8v __attribute__((ext_vector_type(8)));
typedef float f4v __attribute__((ext_vector_type(4)));
typedef float f16v __attribute__((ext_vector_type(16)));

__device__ __forceinline__ ushort f2b(float f) {
    union { float f; unsigned u; } x; x.f = f;
    unsigned r = x.u + 0x7fffu + ((x.u >> 16) & 1u);   // RNE, inputs finite
    return (ushort)(r >> 16);
}

// ---- fragment-order layouts (all loads in attn/proj-B are wave-contiguous) ----
// wt [which][ctile(8)][ks(16)][hi(2)][col(32)][j(8)]:  = bf16(W[ks*16+hi*8+j][ctile*32+col])
// qh [bh][qb(64)][hi(2)][l31(32)][j(8)]: q-row qb*32+l31, d = hi*8+j  (pre-scaled)
// kh [bh][t (64)][hi(2)][l31(32)][j(8)]: k-row t*32+l31, d = hi*8+j
// vt [bh][t (64)][half(2)][hi(2)][d(16)][j(8)]: V^T[d][k = t*32+half*16+hi*8+j]

// -------- one-shot: W (f32, [k][n]) -> wt fragment layout --------
__global__ __launch_bounds__(256) void wtrans_kernel(
    const float* __restrict__ WQ, const float* __restrict__ WK,
    const float* __restrict__ WV, ushort* __restrict__ wt)
{
    const int which = blockIdx.y;
    const float* W = (which == 0) ? WQ : (which == 1) ? WK : WV;
    ushort* o = wt + which * (IN_D * NHEAD * HDIM);
    const int tid = threadIdx.x;
    const int n  = blockIdx.x * 16 + (tid & 15);
    const int ks = tid >> 4;                    // k-chunk of 16
    ushort tmp[16];
#pragma unroll
    for (int j = 0; j < 16; ++j)
        tmp[j] = f2b(W[(ks * 16 + j) * (NHEAD * HDIM) + n]);   // coalesced reads per j
    const size_t base = (size_t)(n >> 5) * 8192 + ks * 512 + (n & 31) * 8;
    *(s8v*)(o + base)       = *(const s8v*)&tmp[0];   // hi=0
    *(s8v*)(o + base + 256) = *(const s8v*)&tmp[8];   // hi=1
}

// -------- projection: block = 4 waves x 32 rows; wave = 2 col-chains of 32 --------
// B-loads contiguous 1KB/wave from wt; A-loads direct (shared by both chains).
// which=0: qh*(0.25*log2e)  which=1: kh  which=2: vt
__global__ __launch_bounds__(256, 4) void proj_kernel(
    const float* __restrict__ Q, const float* __restrict__ K, const float* __restrict__ V,
    const ushort* __restrict__ wt,
    ushort* __restrict__ qh, ushort* __restrict__ kh, ushort* __restrict__ vt)
{
    const int which = blockIdx.y;
    const float* X = (which == 0) ? Q : (which == 1) ? K : V;
    const ushort* wb = wt + which * (IN_D * NHEAD * HDIM);

    const int tid = threadIdx.x;
    const int wv = tid >> 6, lane = tid & 63;
    const int l31 = lane & 31, hi = lane >> 5;
    const int rt = blockIdx.x;                    // 128 row-tiles of 32
    const int rowA = rt * 32 + l31;

    const ushort* w0 = wb + (size_t)(wv * 2 + 0) * 8192 + hi * 256 + l31 * 8;
    const ushort* w1 = wb + (size_t)(wv * 2 + 1) * 8192 + hi * 256 + l31 * 8;

    f16v acc0 = {}, acc1 = {};
#pragma unroll 4
    for (int ks = 0; ks < 16; ++ks) {
        const float* xp = X + (size_t)rowA * IN_D + ks * 16 + 8 * hi;
        const f4v x0 = *(const f4v*)xp;
        const f4v x1 = *(const f4v*)(xp + 4);
        union { unsigned u[4]; s8v v; } au;
        asm("v_cvt_pk_bf16_f32 %0, %1, %2" : "=v"(au.u[0]) : "v"(x0[0]), "v"(x0[1]));
        asm("v_cvt_pk_bf16_f32 %0, %1, %2" : "=v"(au.u[1]) : "v"(x0[2]), "v"(x0[3]));
        asm("v_cvt_pk_bf16_f32 %0, %1, %2" : "=v"(au.u[2]) : "v"(x1[0]), "v"(x1[1]));
        asm("v_cvt_pk_bf16_f32 %0, %1, %2" : "=v"(au.u[3]) : "v"(x1[2]), "v"(x1[3]));
        const s8v b0 = *(const s8v*)(w0 + ks * 512);
        const s8v b1 = *(const s8v*)(w1 + ks * 512);
        acc0 = __builtin_amdgcn_mfma_f32_32x32x16_bf16(au.v, b0, acc0, 0, 0, 0);
        acc1 = __builtin_amdgcn_mfma_f32_32x32x16_bf16(au.v, b1, acc1, 0, 0, 0);
    }

    // C layout: col = lane&31 (= n within tile), row s = rt*32 + (r&3)+8*(r>>2)+4*hi
    const int qbt = rt & 63;                      // row-tile within batch
    const int bI  = rt >> 6;
    auto store_chain = [&](const f16v& A, int c) {
        const int n = (wv * 2 + c) * 32 + l31;
        const int h = n >> 4, d = n & 15;
        const int bh = bI * NHEAD + h;
        if (which == 2) {
            ushort* vb = vt + (size_t)bh * 32768 + qbt * 512 + d * 8 + 4 * hi;
#pragma unroll
            for (int g = 0; g < 4; ++g) {         // regs 4g..4g+3 -> j consecutive
                unsigned long long pk = 0;
#pragma unroll
                for (int j = 0; j < 4; ++j)
                    pk |= (unsigned long long)f2b(A[g * 4 + j]) << (16 * j);
                *(unsigned long long*)(vb + (g >> 1) * 256 + (g & 1) * 128) = pk;
            }
        } else {
            ushort* dst = ((which == 0) ? qh : kh) +
                          (size_t)bh * 32768 + qbt * 512 + (d >> 3) * 256 + (d & 7);
            const float scale = (which == 0) ? 0.25f * 1.44269504f : 1.0f;  // 1/sqrt(D)*log2e
#pragma unroll
            for (int r = 0; r < 16; ++r) {
                const int l31s = (r & 3) + 8 * (r >> 2) + 4 * hi;
                dst[l31s * 8] = f2b(A[r] * scale);
            }
        }
    };
    store_chain(acc0, 0);
    store_chain(acc1, 1);
}

// ---- causal attention: block = 4 waves, paired q-blocks (i, 63-i) = 65 work items ----
// All loads wave-contiguous (fragment-order layouts). Work item = (stream, k-tile);
// wave wv takes items {8j+2wv, 8j+2wv+1}: 2 independent chains/iter + 4 waves/SIMD.
// No max tracking (scores ~N(0,~1.44) in log2 units; exp2 can't overflow; scale cancels).
// l is FREE from PV MFMA: V^T rows 16,20 = 1.0 so acc[8] = sum_k p[k][q] every lane.
__global__ __launch_bounds__(256, 4) void attn_kernel(
    const ushort* __restrict__ qh, const ushort* __restrict__ kh,
    const ushort* __restrict__ vt, float* __restrict__ out)
{
    __shared__ float ol[2][4][8][64];
    __shared__ float ll[2][4][32];
    const int tid = threadIdx.x;
    const int wv = tid >> 6, lane = tid & 63;
    const int l31 = lane & 31, hi = lane >> 5;
    const int bh = blockIdx.y;
    const int qbA = blockIdx.x;                 // light stream
    const int qbB = 63 - qbA;                   // heavy stream
    const int ntA = qbA + 1, ntB = qbB + 1;     // ntA + ntB == 65

    const ushort* qp = qh + (size_t)bh * 32768;
    const ushort* kp = kh + (size_t)bh * 32768;
    const ushort* vp = vt + (size_t)bh * 32768;

    const s8v qfA = *(const s8v*)(qp + qbA * 512 + hi * 256 + l31 * 8);
    const s8v qfB = *(const s8v*)(qp + qbB * 512 + hi * 256 + l31 * 8);
    const f16v z16 = {};
    f16v aA0 = {}, aA1 = {}, aB0 = {}, aB1 = {};

    // V rows 16,20 = 1.0 (bf16) -> acc[8] accumulates the softmax denominator
    s8v vinit = {};
    if (l31 == 16 || l31 == 20) {
#pragma unroll
        for (int j = 0; j < 8; ++j) vinit[j] = (short)0x3F80;
    }

    auto process = [&](int it) {
        const bool isB = (it < ntB);            // block/wave-uniform
        const int t  = isB ? it : it - ntB;
        const s8v kf = *(const s8v*)(kp + t * 512 + hi * 256 + l31 * 8);
        s8v vf0 = vinit, vf1 = vinit;
        if (l31 < 16) {
            vf0 = *(const s8v*)(vp + t * 512 + hi * 128 + l31 * 8);
            vf1 = *(const s8v*)(vp + t * 512 + 256 + hi * 128 + l31 * 8);
        }
        const s8v qf = isB ? qfB : qfA;
        const int nt = isB ? ntB : ntA;
        const f16v st = __builtin_amdgcn_mfma_f32_32x32x16_bf16(kf, qf, z16, 0, 0, 0);
        float p[16];
#pragma unroll
        for (int r = 0; r < 16; ++r) p[r] = __builtin_amdgcn_exp2f(st[r]);
        if (t == nt - 1) {                      // diagonal tile: zero k > q
#pragma unroll
            for (int r = 0; r < 16; ++r) {
                const int kr = (r & 3) + 8 * (r >> 2) + 4 * hi;
                if (kr > l31) p[r] = 0.f;
            }
        }
        s8v pb[2];
#pragma unroll
        for (int half = 0; half < 2; ++half) {
            unsigned x0, x1, y0, y1;
            asm("v_cvt_pk_bf16_f32 %0, %1, %2" : "=v"(x0) : "v"(p[8*half+0]), "v"(p[8*half+1]));
            asm("v_cvt_pk_bf16_f32 %0, %1, %2" : "=v"(x1) : "v"(p[8*half+2]), "v"(p[8*half+3]));
            asm("v_cvt_pk_bf16_f32 %0, %1, %2" : "=v"(y0) : "v"(p[8*half+4]), "v"(p[8*half+5]));
            asm("v_cvt_pk_bf16_f32 %0, %1, %2" : "=v"(y1) : "v"(p[8*half+6]), "v"(p[8*half+7]));
            auto r0 = __builtin_amdgcn_permlane32_swap(x0, y0, false, false);
            auto r1 = __builtin_amdgcn_permlane32_swap(x1, y1, false, false);
            union { unsigned u[4]; s8v v; } bu;
            bu.u[0] = r0[0]; bu.u[1] = r1[0]; bu.u[2] = r0[1]; bu.u[3] = r1[1];
            pb[half] = bu.v;
        }
        __builtin_amdgcn_s_setprio(1);
        if (isB) {
            aB0 = __builtin_amdgcn_mfma_f32_32x32x16_bf16(vf0, pb[0], aB0, 0, 0, 0);
            aB1 = __builtin_amdgcn_mfma_f32_32x32x16_bf16(vf1, pb[1], aB1, 0, 0, 0);
        } else {
            aA0 = __builtin_amdgcn_mfma_f32_32x32x16_bf16(vf0, pb[0], aA0, 0, 0, 0);
            aA1 = __builtin_amdgcn_mfma_f32_32x32x16_bf16(vf1, pb[1], aA1, 0, 0, 0);
        }
        __builtin_amdgcn_s_setprio(0);
    };

    for (int it0 = 2 * wv; it0 < 65; it0 += 8) {   // two independent items per iteration
        process(it0);
        if (it0 + 1 < 65) process(it0 + 1);
    }

    // per-wave raw partials -> LDS (conflict-free: lane is fastest index)
#pragma unroll
    for (int j = 0; j < 8; ++j) {
        ol[0][wv][j][lane] = aB0[j] + aB1[j];
        ol[1][wv][j][lane] = aA0[j] + aA1[j];
    }
    if (hi == 0) {                               // acc[8] = denominator (rows 16/20 of V=1)
        ll[0][wv][l31] = aB0[8] + aB1[8];
        ll[1][wv][l31] = aA0[8] + aA1[8];
    }
    __syncthreads();

    if (wv < 2) {                               // wave 0 -> stream B, wave 1 -> stream A
        const int ss = wv;
        const int qw = (ss ? qbA : qbB) * 32;
        float l = (ll[ss][0][l31] + ll[ss][1][l31]) + (ll[ss][2][l31] + ll[ss][3][l31]);
        const float inv = __builtin_amdgcn_rcpf(l);
        float o[8];
#pragma unroll
        for (int j = 0; j < 8; ++j)
            o[j] = ((ol[ss][0][j][lane] + ol[ss][1][j][lane]) +
                    (ol[ss][2][j][lane] + ol[ss][3][j][lane])) * inv;
        const int b = bh >> 4, h = bh & 15;
        f4v o0, o1;
#pragma unroll
        for (int j = 0; j < 4; ++j) { o0[j] = o[j]; o1[j] = o[4 + j]; }
        float* op = out + ((size_t)b * S_LEN + qw + l31) * (NHEAD * HDIM) + h * HDIM;
        *(f4v*)(op + 4 * hi) = o0;        // d = 4*hi + 0..3
        *(f4v*)(op + 8 + 4 * hi) = o1;    // d = 8 + 4*hi + 0..3
    }
}

extern "C" void kernel_launch(void* const* d_in, const int* in_sizes, int n_in,
                              void* d_out, int out_size, void* d_ws, size_t ws_size,
                              hipStream_t stream)
{
    const float* Q  = (const float*)d_in[0];
    const float* K  = (const float*)d_in[1];
    const float* V  = (const float*)d_in[2];
    const float* WQ = (const float*)d_in[3];
    const float* WK = (const float*)d_in[4];
    const float* WV = (const float*)d_in[5];
    float* out = (float*)d_out;

    const size_t mat = (size_t)2 * NHEAD * S_LEN * HDIM;   // 2 MB bf16 each
    ushort* qh = (ushort*)d_ws;
    ushort* kh = qh + mat;
    ushort* vt = kh + mat;
    ushort* wt = vt + mat;                                  // 3 x 128 KB

    wtrans_kernel<<<dim3(16, 3), 256, 0, stream>>>(WQ, WK, WV, wt);
    proj_kernel<<<dim3(128, 3), 256, 0, stream>>>(Q, K, V, wt, qh, kh, vt);
    attn_kernel<<<dim3(S_LEN / 64, 2 * NHEAD), 256, 0, stream>>>(qh, kh, vt, out);
}